// Round 14
// baseline (175.145 us; speedup 1.0000x reference)
//
#include <hip/hip_runtime.h>
#include <cstdint>

#define Bz 8
#define Nn 1024
#define Cc 768
#define Hh 12
#define Dd 64
#define C3 2304
#define BN 8192

constexpr float EPS = 1e-5f;
// q scale folded with log2(e): softmax exp(S) == exp2(S*log2e), fold into q
constexpr float QSCALE = 0.125f * 1.44269504088896340736f;

typedef __attribute__((ext_vector_type(8))) short bf16x8;
typedef _Float16 f16x8 __attribute__((ext_vector_type(8)));
typedef __attribute__((ext_vector_type(4))) float f32x4;
typedef __attribute__((ext_vector_type(16))) float f32x16;

__device__ __forceinline__ short f2b(float f) {
    union { float f; unsigned u; } x; x.f = f;
    unsigned r = x.u + 0x7FFFu + ((x.u >> 16) & 1u);   // RNE to bf16
    return (short)(r >> 16);
}
__device__ __forceinline__ unsigned cvtpk(float a, float b) {   // (lo=a, hi=b) bf16 pair, RNE
    unsigned r;
    asm("v_cvt_pk_bf16_f32 %0, %1, %2" : "=v"(r) : "v"(a), "v"(b));
    return r;
}
__device__ __forceinline__ unsigned pkrtz(float a, float b) {   // (lo=a, hi=b) fp16 pair, RTZ
    auto h = __builtin_amdgcn_cvt_pkrtz(a, b);
    union { decltype(h) v; unsigned u; } x; x.v = h;
    return x.u;
}

__device__ __forceinline__ f32x4 MFMAH(f16x8 a, f16x8 b, f32x4 c) {
    return __builtin_amdgcn_mfma_f32_16x16x32_f16(a, b, c, 0, 0, 0);
}
__device__ __forceinline__ f32x16 MFMA32(bf16x8 a, bf16x8 b, f32x16 c) {
    return __builtin_amdgcn_mfma_f32_32x32x16_bf16(a, b, c, 0, 0, 0);
}
__device__ __forceinline__ f16x8 ldf16(const _Float16* p) { return *(const f16x8*)p; }
// async global->LDS, 16B per lane; lds dst is wave-uniform base (+lane*16 by HW)
__device__ __forceinline__ void gld16(const void* g, void* l) {
    __builtin_amdgcn_global_load_lds((const __attribute__((address_space(1))) unsigned int*)g,
                                     (__attribute__((address_space(3))) unsigned int*)(l),
                                     16, 0, 0);
}

// ---------------- fp32 -> fp16 convert of qkv_w, proj_w only (x handled in-GEMM) --------
__global__ __launch_bounds__(256) void cvt_w(
    const float* __restrict__ wq, const float* __restrict__ wp,
    _Float16* __restrict__ wqh, _Float16* __restrict__ wph)
{
    const int n1 = C3 * Cc / 8, n2 = n1 + Cc * Cc / 8;
    int i = blockIdx.x * 256 + threadIdx.x;
    const float* s; _Float16* d; int off;
    if (i < n1)      { s = wq; d = wqh; off = i; }
    else if (i < n2) { s = wp; d = wph; off = i - n1; }
    else return;
    float4 a = *(const float4*)(s + (size_t)off * 8);
    float4 b = *(const float4*)(s + (size_t)off * 8 + 4);
    f16x8 o;
    o[0] = (_Float16)a.x; o[1] = (_Float16)a.y; o[2] = (_Float16)a.z; o[3] = (_Float16)a.w;
    o[4] = (_Float16)b.x; o[5] = (_Float16)b.y; o[6] = (_Float16)b.z; o[7] = (_Float16)b.w;
    *(f16x8*)(d + (size_t)off * 8) = o;
}

// ---------------- fp16 MFMA GEMM NT, m97 pattern (single 32KB LDS buffer) ----------------
// EPI=1: A is fp32 (x), converted in-register during staging (aload early / acommit late);
//        epilogue = bias + fused LN -> bf16 q/k/v planes.
// EPI=0: A is fp16 (att), gld16-staged; epilogue = fp32 out + bias (proj).
template<int EPI>
__global__ __launch_bounds__(256, 3) void gemm_f16(
    const void* __restrict__ Ain,
    const _Float16* __restrict__ W,
    const float* __restrict__ bias,
    float* __restrict__ Out,
    short* __restrict__ qp, short* __restrict__ kp, short* __restrict__ vp,
    const float* __restrict__ qg, const float* __restrict__ qb,
    const float* __restrict__ kg, const float* __restrict__ kb,
    int nx)
{
    __shared__ _Float16 As[128 * 64];   // [row][64k], 128B rows, 8-slot swizzle ^(row&7)
    __shared__ _Float16 Bs[128 * 64];
    const int tid = threadIdx.x;
    const int lane = tid & 63;
    const int w = tid >> 6;
    const int wr = w >> 1, wc = w & 1;
    const int l15 = lane & 15, l4 = lane >> 4;
    const int lr = lane >> 3;
    const int lslot = lane & 7;
    const _Float16* A16 = (const _Float16*)Ain;
    const float*    A32 = (const float*)Ain;
    // A reg-staging coords (EPI1): thread owns half a row (32 floats)
    const int arow = tid >> 1;
    const int akq  = (tid & 1) * 32;

    const int chunk = gridDim.x >> 3;
    const int wg = (blockIdx.x & 7) * chunk + (blockIdx.x >> 3);
    const int by = wg / nx;
    int bx = wg % nx;
    if (by & 1) bx = nx - 1 - bx;
    const int m0 = by * 128;
    const int n0 = bx * 128;

    auto stageB = [&](int kt) {            // 16 x 1KB gld16 issues, 4 per wave
        const int k0 = kt * 64;
#pragma unroll
        for (int j = 0; j < 4; ++j) {
            int ib = w * 4 + j;
            int row = ib * 8 + lr;
            int gslot = lslot ^ (row & 7);
            gld16(W + (size_t)(n0 + row) * 768 + k0 + gslot * 8, Bs + ib * 512);
        }
    };
    auto stageA16 = [&](int kt) {          // EPI0: A fp16 via gld16
        const int k0 = kt * 64;
#pragma unroll
        for (int j = 0; j < 4; ++j) {
            int ib = w * 4 + j;
            int row = ib * 8 + lr;
            int gslot = lslot ^ (row & 7);
            gld16(A16 + (size_t)(m0 + row) * 768 + k0 + gslot * 8, As + ib * 512);
        }
    };
    auto aload = [&](int kt, float4* ar) { // EPI1: issue A fp32 loads (no LDS touch)
        const float* src = A32 + (size_t)(m0 + arow) * 768 + kt * 64 + akq;
#pragma unroll
        for (int j = 0; j < 8; ++j) ar[j] = ((const float4*)src)[j];
    };
    auto acommit = [&](const float4* ar) { // EPI1: cvt_pkrtz pack + swizzled b128 writes
#pragma unroll
        for (int i = 0; i < 4; ++i) {
            union { unsigned u[4]; f16x8 v; } u;
            u.u[0] = pkrtz(ar[2 * i].x,     ar[2 * i].y);
            u.u[1] = pkrtz(ar[2 * i].z,     ar[2 * i].w);
            u.u[2] = pkrtz(ar[2 * i + 1].x, ar[2 * i + 1].y);
            u.u[3] = pkrtz(ar[2 * i + 1].z, ar[2 * i + 1].w);
            int s = ((akq >> 3) + i) ^ (arow & 7);
            *(f16x8*)&As[arow * 64 + s * 8] = u.v;
        }
    };

    f32x4 acc[4][4];
#pragma unroll
    for (int mi = 0; mi < 4; ++mi)
#pragma unroll
        for (int ni = 0; ni < 4; ++ni) { acc[mi][ni][0]=0.f; acc[mi][ni][1]=0.f; acc[mi][ni][2]=0.f; acc[mi][ni][3]=0.f; }

    // prologue: stage tile 0
    if (EPI == 1) { float4 ar0[8]; aload(0, ar0); acommit(ar0); }
    else stageA16(0);
    stageB(0);

    float4 ar[8];
    for (int kt = 0; kt < 12; ++kt) {
        __syncthreads();                   // tile kt ready (drains gld16 + A ds_writes)
        if (EPI == 1 && kt < 11) aload(kt + 1, ar);   // A loads fly during compute
#pragma unroll
        for (int ks = 0; ks < 2; ++ks) {
            f16x8 af[4], bfr[4];
#pragma unroll
            for (int mi = 0; mi < 4; ++mi) {
                int row = wr * 64 + mi * 16 + l15;
                int slot = (ks * 4 + l4) ^ (row & 7);
                af[mi] = ldf16(&As[row * 64 + slot * 8]);
            }
#pragma unroll
            for (int ni = 0; ni < 4; ++ni) {
                int row = wc * 64 + ni * 16 + l15;
                int slot = (ks * 4 + l4) ^ (row & 7);
                bfr[ni] = ldf16(&Bs[row * 64 + slot * 8]);
            }
#pragma unroll
            for (int mi = 0; mi < 4; ++mi)
#pragma unroll
                for (int ni = 0; ni < 4; ++ni)
                    acc[mi][ni] = MFMAH(af[mi], bfr[ni], acc[mi][ni]);
        }
        __syncthreads();                   // all reads done -> safe to overwrite
        if (kt < 11) {
            if (EPI == 1) acommit(ar); else stageA16(kt + 1);
            stageB(kt + 1);
        }
    }

    if (EPI == 0) {
#pragma unroll
        for (int mi = 0; mi < 4; ++mi)
#pragma unroll
            for (int r = 0; r < 4; ++r) {
                int row = m0 + wr * 64 + mi * 16 + l4 * 4 + r;
#pragma unroll
                for (int ni = 0; ni < 4; ++ni) {
                    int col = n0 + wc * 64 + ni * 16 + l15;
                    Out[(size_t)row * Cc + col] = acc[mi][ni][r] + bias[col];
                }
            }
    } else {
        const int ncol0 = n0 + wc * 64;
        const int type = ncol0 / Cc;           // 0=q 1=k 2=v
        const int h = (ncol0 % Cc) >> 6;
        const float* gptr = (type == 0) ? qg : kg;
        const float* bptr = (type == 0) ? qb : kb;
        float biasv[4], gv[4], bv[4];
#pragma unroll
        for (int ni = 0; ni < 4; ++ni) {
            int d = ni * 16 + l15;
            biasv[ni] = bias[ncol0 + d];
            if (type < 2) { gv[ni] = gptr[d]; bv[ni] = bptr[d]; }
        }
        short* plane = (type == 0) ? qp : (type == 1) ? kp : vp;
#pragma unroll
        for (int mi = 0; mi < 4; ++mi)
#pragma unroll
            for (int r = 0; r < 4; ++r) {
                float v[4];
#pragma unroll
                for (int ni = 0; ni < 4; ++ni) v[ni] = acc[mi][ni][r] + biasv[ni];
                int row = m0 + wr * 64 + mi * 16 + l4 * 4 + r;
                size_t base = ((size_t)row * Hh + h) * 64;
                if (type < 2) {
                    float s = v[0] + v[1] + v[2] + v[3];
#pragma unroll
                    for (int off = 1; off < 16; off <<= 1) s += __shfl_xor(s, off);
                    float mu = s * (1.0f / 64.0f);
                    float s2 = 0.f;
#pragma unroll
                    for (int ni = 0; ni < 4; ++ni) { float dv = v[ni] - mu; s2 += dv * dv; }
#pragma unroll
                    for (int off = 1; off < 16; off <<= 1) s2 += __shfl_xor(s2, off);
                    float inv = rsqrtf(s2 * (1.0f / 64.0f) + EPS);
#pragma unroll
                    for (int ni = 0; ni < 4; ++ni) {
                        float rr = (v[ni] - mu) * inv * gv[ni] + bv[ni];
                        if (type == 0) rr *= QSCALE;
                        plane[base + ni * 16 + l15] = f2b(rr);
                    }
                } else {
#pragma unroll
                    for (int ni = 0; ni < 4; ++ni)
                        plane[base + ni * 16 + l15] = f2b(v[ni]);
                }
            }
    }
}

// ---------------- Flash attention: r10 winner (4 waves, KVBLK=64, sigma-trick P) ----------
// S^T = mfma(K,Q): lane q=l31 holds P[k][q] lane-locally; softmax per-lane scalar.
// cvt_pk pairs ARE the PV A-fragment (lane-independent permutation sigma of the MFMA
// k-index: swap ranges 4-7 <-> 8-11 per 16-block); V^T staged sigma-permuted.
__global__ __launch_bounds__(256, 4) void flash_attn_mfma(
    const short* __restrict__ qp, const short* __restrict__ kp, const short* __restrict__ vp,
    _Float16* __restrict__ att)
{
    __shared__ short kls[2][64 * 64];    // K tile [k][d], gld16, slot ^ (row&7)
    __shared__ short vtl[2][64 * 64];    // V^T tile [d][k-sigma], slot ^ fv(d)
    const int tid = threadIdx.x;
    const int lane = tid & 63;
    const int w = tid >> 6;              // 0..3
    const int l31 = lane & 31;
    const int hi = lane >> 5;            // 0/1
    const int lr = lane >> 3;            // 0..7
    const int lslot = lane & 7;
    // XCD-aware swizzle: 768 = 8 XCD * 96 (bijective)
    const int bid = (blockIdx.x & 7) * 96 + (blockIdx.x >> 3);
    const int qt = bid & 7;
    const int bh = bid >> 3;
    const int h = bh % Hh;
    const int b = bh / Hh;
    const int q0 = qt * 128;
    const size_t hbase = ((size_t)b * Nn * Hh + h) * 64;
    // V staging: thread covers k-pair (n0v, n0v+1) x 8 d's
    const int n0v = (tid & 31) * 2, d0v = (tid >> 5) * 8;
    const int khalf = n0v & 31;
    const int t2v = n0v >> 5;
    const int ksig = khalf ^ ((((khalf >> 2) ^ (khalf >> 3)) & 1) * 12);   // sigma (involution)
    const int colv = t2v * 32 + ksig;

    // Q fragments (B-operand of S^T): qf[ds] = Q[q=l31][ds*16 + hi*8 .. +7]
    bf16x8 qf[4];
    {
        const short* qsrc = qp + hbase + (size_t)(q0 + w * 32 + l31) * 768 + hi * 8;
#pragma unroll
        for (int ds = 0; ds < 4; ++ds)
            qf[ds] = *(const bf16x8*)(qsrc + ds * 16);
    }

    auto kstage = [&](int kt, int buf) {
#pragma unroll
        for (int i = 0; i < 2; ++i) {
            int row = i * 32 + w * 8 + lr;
            gld16(kp + hbase + (size_t)(kt * 64 + row) * 768 + (lslot ^ lr) * 8,
                  &kls[buf][(i * 32 + w * 8) * 64]);
        }
    };
    auto vcommit = [&](int buf, bf16x8 a0, bf16x8 a1) {
#pragma unroll
        for (int j = 0; j < 8; ++j) {
            int d = d0v + j;
            int fv = (d ^ (d >> 3)) & 7;
            unsigned pku = (unsigned short)a0[j] | ((unsigned)(unsigned short)a1[j] << 16);
            *(unsigned*)&vtl[buf][d * 64 + (((colv >> 3) ^ fv) << 3) + (colv & 7)] = pku;
        }
    };

    // prologue: stage K0 + V0
    kstage(0, 0);
    {
        const short* s0 = vp + hbase + (size_t)n0v * 768 + d0v;
        vcommit(0, *(const bf16x8*)s0, *(const bf16x8*)(s0 + 768));
    }
    __syncthreads();

    f32x16 o0, o1;
#pragma unroll
    for (int i = 0; i < 16; ++i) { o0[i] = 0.f; o1[i] = 0.f; }
    float lrun = 0.f;

    for (int kt = 0; kt < 16; ++kt) {
        const int cur = kt & 1, nxt = cur ^ 1;
        // T14: issue next K (gld) + next V to regs now; commit V after PV
        bf16x8 va0, va1;
        if (kt < 15) {
            kstage(kt + 1, nxt);
            const short* s0 = vp + hbase + (size_t)((kt + 1) * 64 + n0v) * 768 + d0v;
            va0 = *(const bf16x8*)s0;
            va1 = *(const bf16x8*)(s0 + 768);
        }
        // S^T per 32-k subtile: lane holds P[k][q=l31]; exp2; pack pairs -> A-frags
        unsigned pk[2][8];
#pragma unroll
        for (int t2 = 0; t2 < 2; ++t2) {
            f32x16 st;
#pragma unroll
            for (int i = 0; i < 16; ++i) st[i] = 0.f;
            const int row = t2 * 32 + l31;
            __builtin_amdgcn_s_setprio(1);
#pragma unroll
            for (int ds = 0; ds < 4; ++ds) {
                bf16x8 kf = *(const bf16x8*)&kls[cur][row * 64 + (((ds * 2 + hi) ^ (row & 7)) << 3)];
                st = MFMA32(kf, qf[ds], st);
            }
            __builtin_amdgcn_s_setprio(0);
#pragma unroll
            for (int i = 0; i < 16; ++i) st[i] = exp2f(st[i]);
            {
                float s01 = (st[0] + st[1]) + (st[2] + st[3]);
                float s23 = (st[4] + st[5]) + (st[6] + st[7]);
                float s45 = (st[8] + st[9]) + (st[10] + st[11]);
                float s67 = (st[12] + st[13]) + (st[14] + st[15]);
                lrun += (s01 + s23) + (s45 + s67);
            }
#pragma unroll
            for (int i = 0; i < 8; ++i) pk[t2][i] = cvtpk(st[2 * i], st[2 * i + 1]);
        }
        // O += P V (sigma-compensated V)
        __builtin_amdgcn_s_setprio(1);
#pragma unroll
        for (int t2 = 0; t2 < 2; ++t2)
#pragma unroll
            for (int c = 0; c < 2; ++c) {
                union { bf16x8 v; unsigned u[4]; } a;
                a.u[0] = pk[t2][c * 4 + 0]; a.u[1] = pk[t2][c * 4 + 1];
                a.u[2] = pk[t2][c * 4 + 2]; a.u[3] = pk[t2][c * 4 + 3];
#pragma unroll
                for (int nt = 0; nt < 2; ++nt) {
                    int r = nt * 32 + l31;
                    int fv = (r ^ (r >> 3)) & 7;
                    bf16x8 vf = *(const bf16x8*)&vtl[cur][r * 64 + (((t2 * 4 + c * 2 + hi) ^ fv) << 3)];
                    if (nt == 0) o0 = MFMA32(a.v, vf, o0);
                    else         o1 = MFMA32(a.v, vf, o1);
                }
            }
        __builtin_amdgcn_s_setprio(0);
        // commit prefetched V to the other buffer
        if (kt < 15) vcommit(nxt, va0, va1);
        __syncthreads();
    }

    // epilogue: complete row sums across halves, divide, store fp16
    lrun += __shfl_xor(lrun, 32);
    float linv = 1.0f / lrun;            // inv for q = l31
#pragma unroll
    for (int r = 0; r < 16; ++r) {
        int qr = (r & 3) + 8 * (r >> 2) + 4 * hi;
        float invr = __shfl(linv, qr);
        int row = q0 + w * 32 + qr;
        _Float16* dst = att + (size_t)(b * Nn + row) * Cc + h * 64 + l31;
        dst[0]  = (_Float16)(o0[r] * invr);
        dst[32] = (_Float16)(o1[r] * invr);
    }
}

extern "C" void kernel_launch(void* const* d_in, const int* in_sizes, int n_in,
                              void* d_out, int out_size, void* d_ws, size_t ws_size,
                              hipStream_t stream)
{
    const float* x      = (const float*)d_in[0];
    const float* qkv_w  = (const float*)d_in[1];
    const float* qkv_b  = (const float*)d_in[2];
    const float* qn_g   = (const float*)d_in[3];
    const float* qn_b   = (const float*)d_in[4];
    const float* kn_g   = (const float*)d_in[5];
    const float* kn_b   = (const float*)d_in[6];
    const float* proj_w = (const float*)d_in[7];
    const float* proj_b = (const float*)d_in[8];
    float* out = (float*)d_out;

    char* ws = (char*)d_ws;
    short*    qp  = (short*)(ws);                          // [8192][12][64] bf16
    short*    kp  = (short*)(ws + 12582912);
    short*    vp  = (short*)(ws + 25165824);
    _Float16* att = (_Float16*)(ws + 37748736);            // [8192][768] fp16
    _Float16* wqh = (_Float16*)(ws + 62914560);            // [2304][768] fp16
    _Float16* wph = (_Float16*)(ws + 66453504);            // [768][768] fp16

    // 0) fp32 -> fp16 weight conversions (x converted in-GEMM)
    {
        const int n2 = C3 * Cc / 8 + Cc * Cc / 8;
        cvt_w<<<(n2 + 255) / 256, 256, 0, stream>>>(qkv_w, proj_w, wqh, wph);
    }
    // 1) QKV GEMM (A = x fp32, in-register cvt) + bias + fused LN -> bf16 q/k/v planes
    gemm_f16<1><<<(BN / 128) * (C3 / 128), 256, 0, stream>>>(
        x, wqh, qkv_b, nullptr, qp, kp, vp, qn_g, qn_b, kn_g, kn_b, C3 / 128);
    // 2) flash attention -> fp16 att
    flash_attn_mfma<<<Bz * Hh * 8, 256, 0, stream>>>(qp, kp, vp, att);
    // 3) output projection (A = att fp16) + bias -> fp32 out
    gemm_f16<0><<<(BN / 128) * (Cc / 128), 256, 0, stream>>>(
        att, wph, proj_b, out, nullptr, nullptr, nullptr, nullptr, nullptr, nullptr, nullptr, Cc / 128);
}

// Round 15
// 114.321 us; speedup vs baseline: 1.5320x; 1.5320x over previous
//
#include <hip/hip_runtime.h>
#include <cstdint>

#define Bz 8
#define Nn 1024
#define Cc 768
#define Hh 12
#define Dd 64
#define C3 2304
#define BN 8192

constexpr float EPS = 1e-5f;
// q scale folded with log2(e): softmax exp(S) == exp2(S*log2e), fold into q
constexpr float QSCALE = 0.125f * 1.44269504088896340736f;

typedef __attribute__((ext_vector_type(8))) short bf16x8;
typedef _Float16 f16x8 __attribute__((ext_vector_type(8)));
typedef __attribute__((ext_vector_type(4))) float f32x4;
typedef __attribute__((ext_vector_type(16))) float f32x16;

__device__ __forceinline__ short f2b(float f) {
    union { float f; unsigned u; } x; x.f = f;
    unsigned r = x.u + 0x7FFFu + ((x.u >> 16) & 1u);   // RNE to bf16
    return (short)(r >> 16);
}
__device__ __forceinline__ unsigned cvtpk(float a, float b) {   // (lo=a, hi=b) bf16 pair, RNE
    unsigned r;
    asm("v_cvt_pk_bf16_f32 %0, %1, %2" : "=v"(r) : "v"(a), "v"(b));
    return r;
}
// raw v_exp_f32: args are bounded (|x|<10), skip libm's overflow-guard expansion
__device__ __forceinline__ float fexp2(float x) {
#if __has_builtin(__builtin_amdgcn_exp2f)
    return __builtin_amdgcn_exp2f(x);
#else
    float r; asm("v_exp_f32 %0, %1" : "=v"(r) : "v"(x)); return r;
#endif
}

__device__ __forceinline__ f32x4 MFMAH(f16x8 a, f16x8 b, f32x4 c) {
    return __builtin_amdgcn_mfma_f32_16x16x32_f16(a, b, c, 0, 0, 0);
}
__device__ __forceinline__ f32x16 MFMA32(bf16x8 a, bf16x8 b, f32x16 c) {
    return __builtin_amdgcn_mfma_f32_32x32x16_bf16(a, b, c, 0, 0, 0);
}
__device__ __forceinline__ f16x8 ldf16(const _Float16* p) { return *(const f16x8*)p; }
// async global->LDS, 16B per lane; lds dst is wave-uniform base (+lane*16 by HW)
__device__ __forceinline__ void gld16(const void* g, void* l) {
    __builtin_amdgcn_global_load_lds((const __attribute__((address_space(1))) unsigned int*)g,
                                     (__attribute__((address_space(3))) unsigned int*)(l),
                                     16, 0, 0);
}

// ---------------- fused fp32 -> fp16 convert of x, qkv_w, proj_w ----------------
__global__ __launch_bounds__(256) void cvt_all(
    const float* __restrict__ x, const float* __restrict__ wq, const float* __restrict__ wp,
    _Float16* __restrict__ xh, _Float16* __restrict__ wqh, _Float16* __restrict__ wph)
{
    const int n1 = BN * Cc / 8, n2 = n1 + C3 * Cc / 8, n3 = n2 + Cc * Cc / 8;
    int i = blockIdx.x * 256 + threadIdx.x;
    const float* s; _Float16* d; int off;
    if (i < n1)      { s = x;  d = xh;  off = i; }
    else if (i < n2) { s = wq; d = wqh; off = i - n1; }
    else if (i < n3) { s = wp; d = wph; off = i - n2; }
    else return;
    float4 a = *(const float4*)(s + (size_t)off * 8);
    float4 b = *(const float4*)(s + (size_t)off * 8 + 4);
    f16x8 o;
    o[0] = (_Float16)a.x; o[1] = (_Float16)a.y; o[2] = (_Float16)a.z; o[3] = (_Float16)a.w;
    o[4] = (_Float16)b.x; o[5] = (_Float16)b.y; o[6] = (_Float16)b.z; o[7] = (_Float16)b.w;
    *(f16x8*)(d + (size_t)off * 8) = o;
}

// ---------------- fp16 MFMA GEMM NT, m97 pattern: single 32KB LDS buffer, high occupancy ----
template<int EPI>
__global__ __launch_bounds__(256, 4) void gemm_f16(
    const _Float16* __restrict__ A,
    const _Float16* __restrict__ W,
    const float* __restrict__ bias,
    float* __restrict__ Out,
    short* __restrict__ qp, short* __restrict__ kp, short* __restrict__ vp,
    const float* __restrict__ qg, const float* __restrict__ qb,
    const float* __restrict__ kg, const float* __restrict__ kb,
    int nx)
{
    __shared__ _Float16 As[128 * 64];   // [row][64k], 128B rows, 8-slot swizzle ^(row&7)
    __shared__ _Float16 Bs[128 * 64];
    const int tid = threadIdx.x;
    const int lane = tid & 63;
    const int w = tid >> 6;
    const int wr = w >> 1, wc = w & 1;
    const int l15 = lane & 15, l4 = lane >> 4;
    const int lr = lane >> 3;
    const int lslot = lane & 7;

    const int chunk = gridDim.x >> 3;
    const int wg = (blockIdx.x & 7) * chunk + (blockIdx.x >> 3);
    const int by = wg / nx;
    int bx = wg % nx;
    if (by & 1) bx = nx - 1 - bx;
    const int m0 = by * 128;
    const int n0 = bx * 128;

    auto stage = [&](int kt) {
        const int k0 = kt * 64;
#pragma unroll
        for (int j = 0; j < 8; ++j) {
            int i = w * 8 + j;
            int isA = (i < 16);
            int ib = isA ? i : i - 16;
            int row = ib * 8 + lr;
            int gslot = lslot ^ (row & 7);
            const _Float16* src = (isA ? A + (size_t)(m0 + row) * 768
                                       : W + (size_t)(n0 + row) * 768) + k0 + gslot * 8;
            _Float16* dst = (isA ? As : Bs) + ib * 512;
            gld16(src, dst);
        }
    };

    f32x4 acc[4][4];
#pragma unroll
    for (int mi = 0; mi < 4; ++mi)
#pragma unroll
        for (int ni = 0; ni < 4; ++ni) { acc[mi][ni][0]=0.f; acc[mi][ni][1]=0.f; acc[mi][ni][2]=0.f; acc[mi][ni][3]=0.f; }

    stage(0);
    for (int kt = 0; kt < 12; ++kt) {
        __syncthreads();                   // drains gld16 for tile kt
#pragma unroll
        for (int ks = 0; ks < 2; ++ks) {
            f16x8 af[4], bfr[4];
#pragma unroll
            for (int mi = 0; mi < 4; ++mi) {
                int row = wr * 64 + mi * 16 + l15;
                int slot = (ks * 4 + l4) ^ (row & 7);
                af[mi] = ldf16(&As[row * 64 + slot * 8]);
            }
#pragma unroll
            for (int ni = 0; ni < 4; ++ni) {
                int row = wc * 64 + ni * 16 + l15;
                int slot = (ks * 4 + l4) ^ (row & 7);
                bfr[ni] = ldf16(&Bs[row * 64 + slot * 8]);
            }
#pragma unroll
            for (int mi = 0; mi < 4; ++mi)
#pragma unroll
                for (int ni = 0; ni < 4; ++ni)
                    acc[mi][ni] = MFMAH(af[mi], bfr[ni], acc[mi][ni]);
        }
        __syncthreads();                   // all reads done -> safe to overwrite
        if (kt < 11) stage(kt + 1);        // other resident blocks hide the latency
    }

    if (EPI == 0) {
#pragma unroll
        for (int mi = 0; mi < 4; ++mi)
#pragma unroll
            for (int r = 0; r < 4; ++r) {
                int row = m0 + wr * 64 + mi * 16 + l4 * 4 + r;
#pragma unroll
                for (int ni = 0; ni < 4; ++ni) {
                    int col = n0 + wc * 64 + ni * 16 + l15;
                    Out[(size_t)row * Cc + col] = acc[mi][ni][r] + bias[col];
                }
            }
    } else {
        const int ncol0 = n0 + wc * 64;
        const int type = ncol0 / Cc;           // 0=q 1=k 2=v
        const int h = (ncol0 % Cc) >> 6;
        const float* gptr = (type == 0) ? qg : kg;
        const float* bptr = (type == 0) ? qb : kb;
        float biasv[4], gv[4], bv[4];
#pragma unroll
        for (int ni = 0; ni < 4; ++ni) {
            int d = ni * 16 + l15;
            biasv[ni] = bias[ncol0 + d];
            if (type < 2) { gv[ni] = gptr[d]; bv[ni] = bptr[d]; }
        }
        short* plane = (type == 0) ? qp : (type == 1) ? kp : vp;
#pragma unroll
        for (int mi = 0; mi < 4; ++mi)
#pragma unroll
            for (int r = 0; r < 4; ++r) {
                float v[4];
#pragma unroll
                for (int ni = 0; ni < 4; ++ni) v[ni] = acc[mi][ni][r] + biasv[ni];
                int row = m0 + wr * 64 + mi * 16 + l4 * 4 + r;
                size_t base = ((size_t)row * Hh + h) * 64;
                if (type < 2) {
                    float s = v[0] + v[1] + v[2] + v[3];
#pragma unroll
                    for (int off = 1; off < 16; off <<= 1) s += __shfl_xor(s, off);
                    float mu = s * (1.0f / 64.0f);
                    float s2 = 0.f;
#pragma unroll
                    for (int ni = 0; ni < 4; ++ni) { float dv = v[ni] - mu; s2 += dv * dv; }
#pragma unroll
                    for (int off = 1; off < 16; off <<= 1) s2 += __shfl_xor(s2, off);
                    float inv = rsqrtf(s2 * (1.0f / 64.0f) + EPS);
#pragma unroll
                    for (int ni = 0; ni < 4; ++ni) {
                        float rr = (v[ni] - mu) * inv * gv[ni] + bv[ni];
                        if (type == 0) rr *= QSCALE;
                        plane[base + ni * 16 + l15] = f2b(rr);
                    }
                } else {
#pragma unroll
                    for (int ni = 0; ni < 4; ++ni)
                        plane[base + ni * 16 + l15] = f2b(v[ni]);
                }
            }
    }
}

// ---------------- Flash attention: r10 winner + raw exp2 + v_perm pack + hoisted offsets ----
// S^T = mfma(K,Q): lane q=l31 holds P[k][q] lane-locally; softmax per-lane scalar.
// cvt_pk pairs ARE the PV A-fragment (lane-independent permutation sigma of the MFMA
// k-index: swap ranges 4-7 <-> 8-11 per 16-block); V^T staged sigma-permuted.
__global__ __launch_bounds__(256, 4) void flash_attn_mfma(
    const short* __restrict__ qp, const short* __restrict__ kp, const short* __restrict__ vp,
    _Float16* __restrict__ att)
{
    __shared__ short kls[2][64 * 64];    // K tile [k][d], gld16, slot ^ (row&7)
    __shared__ short vtl[2][64 * 64];    // V^T tile [d][k-sigma], slot ^ fv(d)
    const int tid = threadIdx.x;
    const int lane = tid & 63;
    const int w = tid >> 6;              // 0..3
    const int l31 = lane & 31;
    const int hi = lane >> 5;            // 0/1
    const int lr = lane >> 3;            // 0..7
    const int lslot = lane & 7;
    // XCD-aware swizzle: 768 = 8 XCD * 96 (bijective)
    const int bid = (blockIdx.x & 7) * 96 + (blockIdx.x >> 3);
    const int qt = bid & 7;
    const int bh = bid >> 3;
    const int h = bh % Hh;
    const int b = bh / Hh;
    const int q0 = qt * 128;
    const size_t hbase = ((size_t)b * Nn * Hh + h) * 64;
    // V staging: thread covers k-pair (n0v, n0v+1) x 8 d's
    const int n0v = (tid & 31) * 2, d0v = (tid >> 5) * 8;
    const int khalf = n0v & 31;
    const int t2v = n0v >> 5;
    const int ksig = khalf ^ ((((khalf >> 2) ^ (khalf >> 3)) & 1) * 12);   // sigma (involution)
    const int colv = t2v * 32 + ksig;
    // loop-invariant V-commit LDS offsets (indices are compile-time in unrolled use)
    int voff[8];
#pragma unroll
    for (int j = 0; j < 8; ++j) {
        int d = d0v + j;
        int fv = (d ^ (d >> 3)) & 7;
        voff[j] = d * 64 + (((colv >> 3) ^ fv) << 3) + (colv & 7);
    }

    // Q fragments (B-operand of S^T): qf[ds] = Q[q=l31][ds*16 + hi*8 .. +7]
    bf16x8 qf[4];
    {
        const short* qsrc = qp + hbase + (size_t)(q0 + w * 32 + l31) * 768 + hi * 8;
#pragma unroll
        for (int ds = 0; ds < 4; ++ds)
            qf[ds] = *(const bf16x8*)(qsrc + ds * 16);
    }

    auto kstage = [&](int kt, int buf) {
#pragma unroll
        for (int i = 0; i < 2; ++i) {
            int row = i * 32 + w * 8 + lr;
            gld16(kp + hbase + (size_t)(kt * 64 + row) * 768 + (lslot ^ lr) * 8,
                  &kls[buf][(i * 32 + w * 8) * 64]);
        }
    };
    auto vcommit = [&](int buf, bf16x8 a0, bf16x8 a1) {
        union { bf16x8 v; unsigned u[4]; } x0, x1;
        x0.v = a0; x1.v = a1;
#pragma unroll
        for (int j = 0; j < 8; ++j) {
            unsigned pku = __builtin_amdgcn_perm(x1.u[j >> 1], x0.u[j >> 1],
                                                 (j & 1) ? 0x07060302u : 0x05040100u);
            *(unsigned*)&vtl[buf][voff[j]] = pku;
        }
    };

    // prologue: stage K0 + V0
    kstage(0, 0);
    {
        const short* s0 = vp + hbase + (size_t)n0v * 768 + d0v;
        vcommit(0, *(const bf16x8*)s0, *(const bf16x8*)(s0 + 768));
    }
    __syncthreads();

    f32x16 o0, o1;
#pragma unroll
    for (int i = 0; i < 16; ++i) { o0[i] = 0.f; o1[i] = 0.f; }
    float lrun = 0.f;

    for (int kt = 0; kt < 16; ++kt) {
        const int cur = kt & 1, nxt = cur ^ 1;
        // T14: issue next K (gld) + next V to regs now; commit V after PV
        bf16x8 va0, va1;
        if (kt < 15) {
            kstage(kt + 1, nxt);
            const short* s0 = vp + hbase + (size_t)((kt + 1) * 64 + n0v) * 768 + d0v;
            va0 = *(const bf16x8*)s0;
            va1 = *(const bf16x8*)(s0 + 768);
        }
        // S^T per 32-k subtile: lane holds P[k][q=l31]; exp2; pack pairs -> A-frags
        unsigned pk[2][8];
#pragma unroll
        for (int t2 = 0; t2 < 2; ++t2) {
            f32x16 st;
#pragma unroll
            for (int i = 0; i < 16; ++i) st[i] = 0.f;
            const int row = t2 * 32 + l31;
            __builtin_amdgcn_s_setprio(1);
#pragma unroll
            for (int ds = 0; ds < 4; ++ds) {
                bf16x8 kf = *(const bf16x8*)&kls[cur][row * 64 + (((ds * 2 + hi) ^ (row & 7)) << 3)];
                st = MFMA32(kf, qf[ds], st);
            }
            __builtin_amdgcn_s_setprio(0);
#pragma unroll
            for (int i = 0; i < 16; ++i) st[i] = fexp2(st[i]);
            {
                float s01 = (st[0] + st[1]) + (st[2] + st[3]);
                float s23 = (st[4] + st[5]) + (st[6] + st[7]);
                float s45 = (st[8] + st[9]) + (st[10] + st[11]);
                float s67 = (st[12] + st[13]) + (st[14] + st[15]);
                lrun += (s01 + s23) + (s45 + s67);
            }
#pragma unroll
            for (int i = 0; i < 8; ++i) pk[t2][i] = cvtpk(st[2 * i], st[2 * i + 1]);
        }
        // O += P V (sigma-compensated V)
        __builtin_amdgcn_s_setprio(1);
#pragma unroll
        for (int t2 = 0; t2 < 2; ++t2)
#pragma unroll
            for (int c = 0; c < 2; ++c) {
                union { bf16x8 v; unsigned u[4]; } a;
                a.u[0] = pk[t2][c * 4 + 0]; a.u[1] = pk[t2][c * 4 + 1];
                a.u[2] = pk[t2][c * 4 + 2]; a.u[3] = pk[t2][c * 4 + 3];
#pragma unroll
                for (int nt = 0; nt < 2; ++nt) {
                    int r = nt * 32 + l31;
                    int fv = (r ^ (r >> 3)) & 7;
                    bf16x8 vf = *(const bf16x8*)&vtl[cur][r * 64 + (((t2 * 4 + c * 2 + hi) ^ fv) << 3)];
                    if (nt == 0) o0 = MFMA32(a.v, vf, o0);
                    else         o1 = MFMA32(a.v, vf, o1);
                }
            }
        __builtin_amdgcn_s_setprio(0);
        // commit prefetched V to the other buffer
        if (kt < 15) vcommit(nxt, va0, va1);
        __syncthreads();
    }

    // epilogue: complete row sums across halves, divide, store fp16
    lrun += __shfl_xor(lrun, 32);
    float linv = 1.0f / lrun;            // inv for q = l31
#pragma unroll
    for (int r = 0; r < 16; ++r) {
        int qr = (r & 3) + 8 * (r >> 2) + 4 * hi;
        float invr = __shfl(linv, qr);
        int row = q0 + w * 32 + qr;
        _Float16* dst = att + (size_t)(b * Nn + row) * Cc + h * 64 + l31;
        dst[0]  = (_Float16)(o0[r] * invr);
        dst[32] = (_Float16)(o1[r] * invr);
    }
}

extern "C" void kernel_launch(void* const* d_in, const int* in_sizes, int n_in,
                              void* d_out, int out_size, void* d_ws, size_t ws_size,
                              hipStream_t stream)
{
    const float* x      = (const float*)d_in[0];
    const float* qkv_w  = (const float*)d_in[1];
    const float* qkv_b  = (const float*)d_in[2];
    const float* qn_g   = (const float*)d_in[3];
    const float* qn_b   = (const float*)d_in[4];
    const float* kn_g   = (const float*)d_in[5];
    const float* kn_b   = (const float*)d_in[6];
    const float* proj_w = (const float*)d_in[7];
    const float* proj_b = (const float*)d_in[8];
    float* out = (float*)d_out;

    char* ws = (char*)d_ws;
    short*    qp  = (short*)(ws);                          // [8192][12][64] bf16
    short*    kp  = (short*)(ws + 12582912);
    short*    vp  = (short*)(ws + 25165824);
    _Float16* att = (_Float16*)(ws + 37748736);            // [8192][768] fp16
    _Float16* xh  = (_Float16*)(ws + 50331648);            // [8192][768] fp16
    _Float16* wqh = (_Float16*)(ws + 62914560);            // [2304][768] fp16
    _Float16* wph = (_Float16*)(ws + 66453504);            // [768][768] fp16

    // 0) fused fp32 -> fp16 conversions
    {
        const int n3 = BN * Cc / 8 + C3 * Cc / 8 + Cc * Cc / 8;
        cvt_all<<<(n3 + 255) / 256, 256, 0, stream>>>(x, qkv_w, proj_w, xh, wqh, wph);
    }
    // 1) QKV GEMM + bias + fused LN (q scaled by 0.125*log2e) -> bf16 q/k/v planes
    gemm_f16<1><<<(BN / 128) * (C3 / 128), 256, 0, stream>>>(
        xh, wqh, qkv_b, nullptr, qp, kp, vp, qn_g, qn_b, kn_g, kn_b, C3 / 128);
    // 2) flash attention -> fp16 att
    flash_attn_mfma<<<Bz * Hh * 8, 256, 0, stream>>>(qp, kp, vp, att);
    // 3) output projection + bias -> fp32 out
    gemm_f16<0><<<(BN / 128) * (Cc / 128), 256, 0, stream>>>(
        att, wph, proj_b, out, nullptr, nullptr, nullptr, nullptr, nullptr, nullptr, nullptr, Cc / 128);
}